// Round 1
// baseline (1106.442 us; speedup 1.0000x reference)
//
#include <hip/hip_runtime.h>
#include <stdint.h>

#define B_    8
#define S_    4096
#define DM_   512
#define DB_   256
#define DN_   256
#define G3_   768
#define OUTC_ 257
#define NPOS_ (B_*S_)
#define SEG_CAP 33024
#define NSLOT 16
#define SCAN_WGS 128
#define SLOT_STRIDE (SCAN_WGS*NSLOT)

typedef __bf16 bf16x8 __attribute__((ext_vector_type(8)));
typedef float  f32x4  __attribute__((ext_vector_type(4)));

__device__ __forceinline__ unsigned short f2bf(float x){
    unsigned u = __float_as_uint(x);
    u = (u + 0x7FFFu + ((u >> 16) & 1u)) >> 16;
    return (unsigned short)u;
}
__device__ __forceinline__ float bf2f(unsigned short h){
    return __uint_as_float(((unsigned)h) << 16);
}
__device__ __forceinline__ float sigf(float x){ return 1.0f/(1.0f+__expf(-x)); }
__device__ __forceinline__ float tanhfast(float x){
    float t = __expf(2.0f*x);
    return 1.0f - 2.0f/(t + 1.0f);
}

// ---------------- prep kernels ----------------

// bc[j] = b_ih[j] + sum_d b_in[d]*W_ih[j][d]
__global__ void k_prep_bc(const float* __restrict__ W_ih, const float* __restrict__ b_ih,
                          const float* __restrict__ b_in, float* __restrict__ bc){
    int j = blockIdx.x*256 + threadIdx.x;
    if (j >= G3_) return;
    float acc = b_ih[j];
    for (int d = 0; d < DN_; d++) acc += b_in[d]*W_ih[j*DN_ + d];
    bc[j] = acc;
}

// WcT[n][dm] = sum_dn W_ih[n][dn]*W_in[dm][dn]   (bf16, [768][512])
__global__ void k_prep_wct(const float* __restrict__ W_in, const float* __restrict__ W_ih,
                           unsigned short* __restrict__ WcT){
    int id = blockIdx.x*256 + threadIdx.x;   // 0..768*512-1
    int n  = id >> 9;
    int dm = id & 511;
    const float4* wi = (const float4*)(W_in + (size_t)dm*DN_);
    const float4* wh = (const float4*)(W_ih + (size_t)n*DN_);
    float acc = 0.f;
    for (int q = 0; q < DN_/4; q++){
        float4 a = wi[q], b = wh[q];
        acc += a.x*b.x + a.y*b.y + a.z*b.z + a.w*b.w;
    }
    WcT[(size_t)n*DM_ + dm] = f2bf(acc);
}

// W_hh -> per-wave MFMA B-fragments. blob[fr][lane][8], fr = w*48 + kf*6 + nf
// B-frag element: lane l supplies B[k][colp] with k = kf*32 + (l>>4)*8 + i,
// colp = w*96 + nf*16 + (l&15); colp = 3*u + g maps to W_hh row g*256+u.
__global__ void k_prep_wfrag(const float* __restrict__ W_hh, unsigned short* __restrict__ blob){
    int id = blockIdx.x*256 + threadIdx.x;   // 0..24575
    int lane = id & 63;
    int fr   = id >> 6;                       // 0..383
    int nf = fr % 6;
    int kf = (fr/6) % 8;
    int w  = fr / 48;
    int colp = w*96 + nf*16 + (lane & 15);
    int u = colp/3, g = colp % 3;
    int row = g*DN_ + u;
    int kbase = kf*32 + (lane >> 4)*8;
    unsigned short* dst = blob + (size_t)fr*512 + lane*8;
    #pragma unroll
    for (int i = 0; i < 8; i++) dst[i] = f2bf(W_hh[(size_t)row*DN_ + kbase + i]);
}

// wv[k] = sum_u W_init[k][u]*W_time[u];  bv = sum_u b_init[u]*W_time[u]
__global__ void k_prep_wv(const float* __restrict__ W_init, const float* __restrict__ b_init,
                          const float* __restrict__ W_time, float* __restrict__ wv,
                          float* __restrict__ bv){
    int k = threadIdx.x;
    float acc = 0.f;
    for (int u = 0; u < DN_; u++) acc += W_init[(size_t)k*DN_ + u]*W_time[u];
    wv[k] = acc;
    if (k == 0){
        float a = 0.f;
        for (int u = 0; u < DN_; u++) a += b_init[u]*W_time[u];
        *bv = a;
    }
}

// ---------------- segment finder ----------------
__global__ void k_finder(const int* __restrict__ bar, int* __restrict__ cnt,
                         int* __restrict__ s_start, int* __restrict__ s_end,
                         int* __restrict__ s_b, int* __restrict__ s_src){
    int id = blockIdx.x*256 + threadIdx.x;   // global position b*S+t
    int b = id >> 12, t = id & (S_-1);
    bool is_start = (t == 0) || (bar[id-1] == 0);
    if (!is_start) return;
    int e = t;
    while (e < S_-1 && bar[b*S_ + e] != 0) e++;
    int idx = atomicAdd(cnt, 1);
    if (idx < SEG_CAP){
        s_start[idx] = t; s_end[idx] = e; s_b[idx] = b;
        s_src[idx] = (t == 0) ? -1 : (id - 1);
    }
}

// ---------------- xg GEMM: xg[m][n] = bf16( sum_k tgt[m][k]*WcT[n][k] + bc[n] ) ----------------
__global__ __launch_bounds__(256) void k_gemm_xg(
        const float* __restrict__ tgt, const unsigned short* __restrict__ WcT,
        const float* __restrict__ bc, unsigned short* __restrict__ xg){
    __shared__ unsigned short a_s[128][40];
    __shared__ unsigned short b_s[128][40];
    int bid = blockIdx.x;
    int m0 = (bid/6)*128, n0 = (bid%6)*128;
    int tid = threadIdx.x;
    int lane = tid & 63, wid = tid >> 6;
    int wm = wid >> 1, wn = wid & 1;
    int l15 = lane & 15, l4 = lane >> 4;
    f32x4 acc[4][4];
    #pragma unroll
    for (int a = 0; a < 4; a++)
        #pragma unroll
        for (int b = 0; b < 4; b++) acc[a][b] = (f32x4){0.f,0.f,0.f,0.f};

    int ar = tid >> 3, ac = (tid & 7)*4;
    int br = tid >> 2, bcl = (tid & 3)*8;

    for (int kk = 0; kk < 16; kk++){
        int k0 = kk*32;
        #pragma unroll
        for (int i = 0; i < 4; i++){
            int r = ar + i*32;
            float4 v = *(const float4*)(tgt + (size_t)(m0+r)*DM_ + k0 + ac);
            ushort4 o = { f2bf(v.x), f2bf(v.y), f2bf(v.z), f2bf(v.w) };
            *(ushort4*)&a_s[r][ac] = o;
        }
        #pragma unroll
        for (int i = 0; i < 2; i++){
            int r = br + i*64;
            uint4 v = *(const uint4*)(WcT + (size_t)(n0+r)*DM_ + k0 + bcl);
            *(uint4*)&b_s[r][bcl] = v;
        }
        __syncthreads();
        bf16x8 af[4], bfr[4];
        #pragma unroll
        for (int mf = 0; mf < 4; mf++) af[mf] = *(const bf16x8*)&a_s[wm*64 + mf*16 + l15][l4*8];
        #pragma unroll
        for (int nf = 0; nf < 4; nf++) bfr[nf] = *(const bf16x8*)&b_s[wn*64 + nf*16 + l15][l4*8];
        #pragma unroll
        for (int mf = 0; mf < 4; mf++)
            #pragma unroll
            for (int nf = 0; nf < 4; nf++)
                acc[mf][nf] = __builtin_amdgcn_mfma_f32_16x16x32_bf16(af[mf], bfr[nf], acc[mf][nf], 0, 0, 0);
        __syncthreads();
    }
    #pragma unroll
    for (int mf = 0; mf < 4; mf++)
        #pragma unroll
        for (int nf = 0; nf < 4; nf++)
            #pragma unroll
            for (int r = 0; r < 4; r++){
                int grow = m0 + wm*64 + mf*16 + l4*4 + r;
                int gcol = n0 + wn*64 + nf*16 + l15;
                float v = acc[mf][nf][r] + bc[gcol];
                xg[(size_t)grow*G3_ + gcol] = f2bf(v);
            }
}

// ---------------- GRU scan over segments ----------------
// 128 WGs x 512 threads (8 waves). 16 slots/WG = M dim of MFMA.
// W_hh fragments register-resident (48 x bf16x8 per lane).
__global__ __launch_bounds__(512) void k_scan(
        const unsigned short* __restrict__ xg,
        const unsigned short* __restrict__ blob,
        const float* __restrict__ hbs,
        const float* __restrict__ W_init, const float* __restrict__ b_init,
        const float* __restrict__ b_hh,
        const int* __restrict__ cnt_p,
        const int* __restrict__ s_start, const int* __restrict__ s_end,
        const int* __restrict__ s_b, const int* __restrict__ s_src,
        float* __restrict__ out)
{
    __shared__ unsigned short Hs[NSLOT*256];     // bf16, XOR-swizzled rows of 512B
    __shared__ float hg[NSLOT][776];             // +8 pad
    __shared__ int st_seg[NSLOT], st_t[NSLOT], st_endv[NSLOT],
                   st_bv[NSLOT], st_init[NSLOT], st_src2[NSLOT];
    __shared__ int act;

    int tid = threadIdx.x;
    int lane = tid & 63, wid = tid >> 6;
    int l15 = lane & 15, l4 = lane >> 4;
    int cnt = *cnt_p; if (cnt > SEG_CAP) cnt = SEG_CAP;

    bf16x8 wf[48];
    #pragma unroll
    for (int f = 0; f < 48; f++)
        wf[f] = *(const bf16x8*)(blob + ((size_t)(wid*48 + f)*64 + lane)*8);

    int u = tid & 255;
    int half = tid >> 8;
    float bhr = b_hh[u], bhz = b_hh[DN_ + u], bhn = b_hh[2*DN_ + u];
    float hreg[8];
    #pragma unroll
    for (int j = 0; j < 8; j++) hreg[j] = 0.f;

    if (tid < NSLOT){
        int g = blockIdx.x*NSLOT + tid;
        if (g < cnt){
            st_seg[tid] = g; st_t[tid] = s_start[g]; st_endv[tid] = s_end[g];
            st_bv[tid] = s_b[g]; st_src2[tid] = s_src[g];
            st_init[tid] = (s_src[g] < 0) ? 1 : 2;
        } else { st_seg[tid] = -1; st_init[tid] = 0; }
    }
    __syncthreads();

    while (true){
        if (tid == 0){
            int a = 0;
            #pragma unroll
            for (int s2 = 0; s2 < NSLOT; s2++) a |= (st_seg[s2] >= 0) ? 1 : 0;
            act = a;
        }
        __syncthreads();
        if (!act) break;

        // init restarted slots (h0 = 0 or h_bar_scatter@W_init + b_init)
        #pragma unroll
        for (int j = 0; j < 8; j++){
            int s = half + (j << 1);
            int fl = st_init[s];
            if (fl == 1){ hreg[j] = 0.f; }
            else if (fl == 2){
                int src = st_src2[s];
                const float* hb = hbs + (size_t)src*DB_;
                float a0 = b_init[u];
                for (int k = 0; k < DB_; k++) a0 += hb[k]*W_init[k*DN_ + u];
                hreg[j] = a0;
            }
        }
        // write H (bf16, swizzled): row=slot, byte = (2u) ^ ((s&7)<<4)
        #pragma unroll
        for (int j = 0; j < 8; j++){
            int s = half + (j << 1);
            int byteoff = (2*u) ^ ((s & 7) << 4);
            *(unsigned short*)((char*)Hs + (s << 9) + byteoff) = f2bf(hreg[j]);
        }
        __syncthreads();

        // hg[slot][colp] = H @ W'   (M=16 slots, K=256, N-slice 96/wave)
        {
            f32x4 acc6[6];
            #pragma unroll
            for (int nf = 0; nf < 6; nf++) acc6[nf] = (f32x4){0.f,0.f,0.f,0.f};
            #pragma unroll
            for (int kf = 0; kf < 8; kf++){
                int boff = (kf*64 + l4*16) ^ ((l15 & 7) << 4);
                bf16x8 a = *(const bf16x8*)((const char*)Hs + (l15 << 9) + boff);
                #pragma unroll
                for (int nf = 0; nf < 6; nf++)
                    acc6[nf] = __builtin_amdgcn_mfma_f32_16x16x32_bf16(a, wf[kf*6 + nf], acc6[nf], 0, 0, 0);
            }
            #pragma unroll
            for (int nf = 0; nf < 6; nf++)
                #pragma unroll
                for (int r = 0; r < 4; r++)
                    hg[l4*4 + r][wid*96 + nf*16 + l15] = acc6[nf][r];
        }
        __syncthreads();

        // gates
        #pragma unroll
        for (int j = 0; j < 8; j++){
            int s = half + (j << 1);
            if (st_seg[s] < 0) continue;
            int t = st_t[s], bb = st_bv[s];
            int row = bb*S_ + t;
            float hgr = hg[s][3*u]     + bhr;
            float hgz = hg[s][3*u + 1] + bhz;
            float hgn = hg[s][3*u + 2] + bhn;
            const unsigned short* xr = xg + (size_t)row*G3_;
            float xrv = bf2f(xr[u]), xzv = bf2f(xr[DN_ + u]), xnv = bf2f(xr[2*DN_ + u]);
            float rr  = sigf(xrv + hgr);
            float zz  = sigf(xzv + hgz);
            float nn2 = tanhfast(xnv + rr*hgn);
            float hn  = (1.f - zz)*nn2 + zz*hreg[j];
            hreg[j] = hn;
            out[(size_t)row*OUTC_ + 1 + u] = hn;
        }
        __syncthreads();

        // state update
        if (tid < NSLOT){
            if (st_seg[tid] >= 0){
                st_init[tid] = 0;
                int t = st_t[tid] + 1;
                if (t > st_endv[tid]){
                    int nx = st_seg[tid] + SLOT_STRIDE;
                    if (nx < cnt){
                        st_seg[tid] = nx; st_t[tid] = s_start[nx]; st_endv[tid] = s_end[nx];
                        st_bv[tid] = s_b[nx]; st_src2[tid] = s_src[nx];
                        st_init[tid] = (s_src[nx] < 0) ? 1 : 2;
                    } else st_seg[tid] = -1;
                } else st_t[tid] = t;
            }
        }
        __syncthreads();
    }
}

// ---------------- time_center ----------------
__global__ void k_tc(float* __restrict__ out,
                     const int* __restrict__ bar, const float* __restrict__ com_t,
                     const float* __restrict__ hbs, const float* __restrict__ wv,
                     const float* __restrict__ bv_p, const float* __restrict__ W_time,
                     const float* __restrict__ b_time)
{
    int wid = threadIdx.x >> 6, lane = threadIdx.x & 63;
    int pos = blockIdx.x*4 + wid;
    int t = pos & (S_-1);
    if (bar[pos] == 0){
        if (lane == 0) out[(size_t)pos*OUTC_] = com_t[pos];
        return;
    }
    float bt = b_time[0];
    if (t == 0){
        if (lane == 0) out[(size_t)pos*OUTC_] = sigf(bt);
        return;
    }
    float dot = 0.f;
    bool barprev = (bar[pos-1] == 0);
    if (barprev){
        const float* hb = hbs + (size_t)(pos-1)*DB_;
        #pragma unroll
        for (int i = 0; i < 4; i++) dot += hb[lane + 64*i]*wv[lane + 64*i];
    } else {
        const float* hp = out + (size_t)(pos-1)*OUTC_ + 1;
        #pragma unroll
        for (int i = 0; i < 4; i++) dot += hp[lane + 64*i]*W_time[lane + 64*i];
    }
    #pragma unroll
    for (int o = 32; o; o >>= 1) dot += __shfl_down(dot, o);
    if (lane == 0){
        if (barprev) dot += *bv_p;
        out[(size_t)pos*OUTC_] = sigf(dot + bt);
    }
}

// ---------------- launch ----------------
extern "C" void kernel_launch(void* const* d_in, const int* in_sizes, int n_in,
                              void* d_out, int out_size, void* d_ws, size_t ws_size,
                              hipStream_t stream) {
    const float* tgt    = (const float*)d_in[0];
    const float* hbs    = (const float*)d_in[1];
    const float* com_t  = (const float*)d_in[2];
    const float* W_in   = (const float*)d_in[3];
    const float* b_in   = (const float*)d_in[4];
    const float* W_init = (const float*)d_in[5];
    const float* b_init = (const float*)d_in[6];
    const float* W_ih   = (const float*)d_in[7];
    const float* b_ih   = (const float*)d_in[8];
    const float* W_hh   = (const float*)d_in[9];
    const float* b_hh   = (const float*)d_in[10];
    const float* W_time = (const float*)d_in[11];
    const float* b_time = (const float*)d_in[12];
    const int*   bar    = (const int*)d_in[13];
    float* out = (float*)d_out;

    char* ws = (char*)d_ws;
    size_t off = 0;
    auto alloc = [&](size_t bytes){ size_t o = off; off += (bytes + 255) & ~(size_t)255; return o; };
    size_t o_xg    = alloc((size_t)NPOS_*G3_*2);      // bf16 xg
    size_t o_wct   = alloc((size_t)G3_*DM_*2);        // bf16 WcT
    size_t o_blob  = alloc((size_t)384*512*2);        // W_hh fragments
    size_t o_bc    = alloc(G3_*4);
    size_t o_wv    = alloc(DN_*4);
    size_t o_bv    = alloc(4);
    size_t o_cnt   = alloc(4);
    size_t o_ss    = alloc(SEG_CAP*4);
    size_t o_se    = alloc(SEG_CAP*4);
    size_t o_sb    = alloc(SEG_CAP*4);
    size_t o_sr    = alloc(SEG_CAP*4);
    (void)ws_size; (void)in_sizes; (void)n_in; (void)out_size;

    unsigned short* xg   = (unsigned short*)(ws + o_xg);
    unsigned short* WcT  = (unsigned short*)(ws + o_wct);
    unsigned short* blob = (unsigned short*)(ws + o_blob);
    float* bc = (float*)(ws + o_bc);
    float* wv = (float*)(ws + o_wv);
    float* bv = (float*)(ws + o_bv);
    int* cnt  = (int*)(ws + o_cnt);
    int* s_start = (int*)(ws + o_ss);
    int* s_end   = (int*)(ws + o_se);
    int* s_b     = (int*)(ws + o_sb);
    int* s_src   = (int*)(ws + o_sr);

    hipMemsetAsync(cnt, 0, 4, stream);

    k_prep_bc   <<<3, 256, 0, stream>>>(W_ih, b_ih, b_in, bc);
    k_prep_wct  <<<(G3_*DM_)/256, 256, 0, stream>>>(W_in, W_ih, WcT);
    k_prep_wfrag<<<96, 256, 0, stream>>>(W_hh, blob);
    k_prep_wv   <<<1, 256, 0, stream>>>(W_init, b_init, W_time, wv, bv);
    k_finder    <<<NPOS_/256, 256, 0, stream>>>(bar, cnt, s_start, s_end, s_b, s_src);
    k_gemm_xg   <<<(NPOS_/128)*6, 256, 0, stream>>>(tgt, WcT, bc, xg);
    k_scan      <<<SCAN_WGS, 512, 0, stream>>>(xg, blob, hbs, W_init, b_init, b_hh,
                                               cnt, s_start, s_end, s_b, s_src, out);
    k_tc        <<<NPOS_/4, 256, 0, stream>>>(out, bar, com_t, hbs, wv, bv, W_time, b_time);
}

// Round 3
// 883.549 us; speedup vs baseline: 1.2523x; 1.2523x over previous
//
#include <hip/hip_runtime.h>
#include <stdint.h>

#define B_    8
#define S_    4096
#define DM_   512
#define DB_   256
#define DN_   256
#define G3_   768
#define OUTC_ 257
#define NPOS_ (B_*S_)
#define SEG_CAP 6144
#define NSLOT 16
#define SCAN_WGS 160
#define SLOT_STRIDE (SCAN_WGS*NSLOT)

typedef __bf16 bf16x8 __attribute__((ext_vector_type(8)));
typedef float  f32x4  __attribute__((ext_vector_type(4)));

__device__ __forceinline__ unsigned short f2bf(float x){
    unsigned u = __float_as_uint(x);
    u = (u + 0x7FFFu + ((u >> 16) & 1u)) >> 16;
    return (unsigned short)u;
}
__device__ __forceinline__ float bf2f(unsigned short h){
    return __uint_as_float(((unsigned)h) << 16);
}
__device__ __forceinline__ float sigf(float x){ return 1.0f/(1.0f+__expf(-x)); }
__device__ __forceinline__ float tanhfast(float x){
    float t = __expf(2.0f*x);
    return 1.0f - 2.0f/(t + 1.0f);
}

// async global -> LDS copy, 4 bytes per lane (lds dest = uniform base + lane*4)
__device__ __forceinline__ void async_cp4(const void* gsrc, void* ldst){
    __builtin_amdgcn_global_load_lds(
        (const __attribute__((address_space(1))) unsigned int*)gsrc,
        (__attribute__((address_space(3))) unsigned int*)ldst, 4, 0, 0);
}

// ---------------- prep kernels ----------------

__global__ void k_prep_bc(const float* __restrict__ W_ih, const float* __restrict__ b_ih,
                          const float* __restrict__ b_in, float* __restrict__ bc){
    int j = blockIdx.x*256 + threadIdx.x;
    if (j >= G3_) return;
    float acc = b_ih[j];
    for (int d = 0; d < DN_; d++) acc += b_in[d]*W_ih[j*DN_ + d];
    bc[j] = acc;
}

__global__ void k_prep_wct(const float* __restrict__ W_in, const float* __restrict__ W_ih,
                           unsigned short* __restrict__ WcT){
    int id = blockIdx.x*256 + threadIdx.x;
    int n  = id >> 9;
    int dm = id & 511;
    const float4* wi = (const float4*)(W_in + (size_t)dm*DN_);
    const float4* wh = (const float4*)(W_ih + (size_t)n*DN_);
    float acc = 0.f;
    for (int q = 0; q < DN_/4; q++){
        float4 a = wi[q], b = wh[q];
        acc += a.x*b.x + a.y*b.y + a.z*b.z + a.w*b.w;
    }
    WcT[(size_t)n*DM_ + dm] = f2bf(acc);
}

// W_hh -> per-wave MFMA B-fragments. blob[fr][lane][8], fr = w*48 + kf*6 + nf
__global__ void k_prep_wfrag(const float* __restrict__ W_hh, unsigned short* __restrict__ blob){
    int id = blockIdx.x*256 + threadIdx.x;
    int lane = id & 63;
    int fr   = id >> 6;
    int nf = fr % 6;
    int kf = (fr/6) % 8;
    int w  = fr / 48;
    int colp = w*96 + nf*16 + (lane & 15);
    int u = colp/3, g = colp % 3;
    int row = g*DN_ + u;
    int kbase = kf*32 + (lane >> 4)*8;
    unsigned short* dst = blob + (size_t)fr*512 + lane*8;
    #pragma unroll
    for (int i = 0; i < 8; i++) dst[i] = f2bf(W_hh[(size_t)row*DN_ + kbase + i]);
}

__global__ void k_prep_wv(const float* __restrict__ W_init, const float* __restrict__ b_init,
                          const float* __restrict__ W_time, float* __restrict__ wv,
                          float* __restrict__ bv){
    int k = threadIdx.x;
    float acc = 0.f;
    for (int u = 0; u < DN_; u++) acc += W_init[(size_t)k*DN_ + u]*W_time[u];
    wv[k] = acc;
    if (k == 0){
        float a = 0.f;
        for (int u = 0; u < DN_; u++) a += b_init[u]*W_time[u];
        *bv = a;
    }
}

// ---------------- segment finder ----------------
__global__ void k_finder(const int* __restrict__ bar, int* __restrict__ cnt,
                         int* __restrict__ s_start, int* __restrict__ s_end,
                         int* __restrict__ s_b, int* __restrict__ s_src){
    int id = blockIdx.x*256 + threadIdx.x;
    int b = id >> 12, t = id & (S_-1);
    bool is_start = (t == 0) || (bar[id-1] == 0);
    if (!is_start) return;
    int e = t;
    while (e < S_-1 && bar[b*S_ + e] != 0) e++;
    int idx = atomicAdd(cnt, 1);
    if (idx < SEG_CAP){
        s_start[idx] = t; s_end[idx] = e; s_b[idx] = b;
        s_src[idx] = (t == 0) ? -1 : (id - 1);
    }
}

// ---------------- reset precompute: reset_buf[i] = hbs[src]@W_init + b_init ----------------
__global__ void k_reset(const float* __restrict__ hbs, const float* __restrict__ W_init,
                        const float* __restrict__ b_init, const int* __restrict__ cnt_p,
                        const int* __restrict__ s_src, float* __restrict__ reset_buf){
    int cnt = *cnt_p; if (cnt > SEG_CAP) cnt = SEG_CAP;
    int u = threadIdx.x;
    for (int i = blockIdx.x; i < cnt; i += gridDim.x){
        int src = s_src[i];
        if (src < 0) continue;
        const float* hb = hbs + (size_t)src*DB_;
        float a0 = b_init[u];
        for (int k = 0; k < DB_; k++) a0 += hb[k]*W_init[(size_t)k*DN_ + u];
        reset_buf[(size_t)i*DN_ + u] = a0;
    }
}

// ---------------- xg GEMM ----------------
__global__ __launch_bounds__(256) void k_gemm_xg(
        const float* __restrict__ tgt, const unsigned short* __restrict__ WcT,
        const float* __restrict__ bc, unsigned short* __restrict__ xg){
    __shared__ unsigned short a_s[128][40];
    __shared__ unsigned short b_s[128][40];
    int bid = blockIdx.x;
    int m0 = (bid/6)*128, n0 = (bid%6)*128;
    int tid = threadIdx.x;
    int lane = tid & 63, wid = tid >> 6;
    int wm = wid >> 1, wn = wid & 1;
    int l15 = lane & 15, l4 = lane >> 4;
    f32x4 acc[4][4];
    #pragma unroll
    for (int a = 0; a < 4; a++)
        #pragma unroll
        for (int b = 0; b < 4; b++) acc[a][b] = (f32x4){0.f,0.f,0.f,0.f};

    int ar = tid >> 3, ac = (tid & 7)*4;
    int br = tid >> 2, bcl = (tid & 3)*8;

    for (int kk = 0; kk < 16; kk++){
        int k0 = kk*32;
        #pragma unroll
        for (int i = 0; i < 4; i++){
            int r = ar + i*32;
            float4 v = *(const float4*)(tgt + (size_t)(m0+r)*DM_ + k0 + ac);
            ushort4 o = { f2bf(v.x), f2bf(v.y), f2bf(v.z), f2bf(v.w) };
            *(ushort4*)&a_s[r][ac] = o;
        }
        #pragma unroll
        for (int i = 0; i < 2; i++){
            int r = br + i*64;
            uint4 v = *(const uint4*)(WcT + (size_t)(n0+r)*DM_ + k0 + bcl);
            *(uint4*)&b_s[r][bcl] = v;
        }
        __syncthreads();
        bf16x8 af[4], bfr[4];
        #pragma unroll
        for (int mf = 0; mf < 4; mf++) af[mf] = *(const bf16x8*)&a_s[wm*64 + mf*16 + l15][l4*8];
        #pragma unroll
        for (int nf = 0; nf < 4; nf++) bfr[nf] = *(const bf16x8*)&b_s[wn*64 + nf*16 + l15][l4*8];
        #pragma unroll
        for (int mf = 0; mf < 4; mf++)
            #pragma unroll
            for (int nf = 0; nf < 4; nf++)
                acc[mf][nf] = __builtin_amdgcn_mfma_f32_16x16x32_bf16(af[mf], bfr[nf], acc[mf][nf], 0, 0, 0);
        __syncthreads();
    }
    #pragma unroll
    for (int mf = 0; mf < 4; mf++)
        #pragma unroll
        for (int nf = 0; nf < 4; nf++)
            #pragma unroll
            for (int r = 0; r < 4; r++){
                int grow = m0 + wm*64 + mf*16 + l4*4 + r;
                int gcol = n0 + wn*64 + nf*16 + l15;
                float v = acc[mf][nf][r] + bc[gcol];
                xg[(size_t)grow*G3_ + gcol] = f2bf(v);
            }
}

// ---------------- GRU scan ----------------
// 160 WGs x 512 threads (8 waves), 16 slots/WG. W_hh fragments register-resident
// (192 VGPRs) -- __launch_bounds__(512,2) caps at 256 VGPR so they do NOT spill.
__global__ __launch_bounds__(512, 2) void k_scan(
        const unsigned short* __restrict__ xg,
        const unsigned short* __restrict__ blob,
        const float* __restrict__ reset_buf,
        const float* __restrict__ b_hh,
        const int* __restrict__ cnt_p,
        const int* __restrict__ s_start, const int* __restrict__ s_end,
        const int* __restrict__ s_b, const int* __restrict__ s_src,
        float* __restrict__ out)
{
    __shared__ unsigned short Hs[NSLOT*256];       // bf16, XOR-swizzled rows of 512B
    __shared__ float hg[NSLOT][776];               // +8 pad
    __shared__ unsigned short xgbuf[NSLOT][G3_];   // prefetched xg rows (24 KB)
    __shared__ int st_seg[NSLOT], st_t[NSLOT], st_endv[NSLOT],
                   st_bv[NSLOT], st_init[NSLOT];

    int tid = threadIdx.x;
    int lane = tid & 63, wid = tid >> 6;
    int l15 = lane & 15, l4 = lane >> 4;
    int cnt = *cnt_p; if (cnt > SEG_CAP) cnt = SEG_CAP;

    bf16x8 wf[48];
    #pragma unroll
    for (int f = 0; f < 48; f++)
        wf[f] = *(const bf16x8*)(blob + ((size_t)(wid*48 + f)*64 + lane)*8);

    int u = tid & 255;
    int half = tid >> 8;
    float bhr = b_hh[u], bhz = b_hh[DN_ + u], bhn = b_hh[2*DN_ + u];
    float hreg[8];
    #pragma unroll
    for (int j = 0; j < 8; j++) hreg[j] = 0.f;

    if (tid < NSLOT){
        int g = blockIdx.x*NSLOT + tid;
        if (g < cnt){
            st_seg[tid] = g; st_t[tid] = s_start[g]; st_endv[tid] = s_end[g];
            st_bv[tid] = s_b[g];
            st_init[tid] = (s_src[g] < 0) ? 1 : 2;
        } else { st_seg[tid] = -1; st_init[tid] = 0; }
    }
    __syncthreads();

    while (true){
        // (B) init restarted slots from precomputed reset_buf
        #pragma unroll
        for (int j = 0; j < 8; j++){
            int s = half + (j << 1);
            int fl = st_init[s];
            if (fl == 1) hreg[j] = 0.f;
            else if (fl == 2) hreg[j] = reset_buf[(size_t)st_seg[s]*DN_ + u];
        }
        // (C) write H (bf16, swizzled): byte = (2u) ^ ((s&7)<<4)
        #pragma unroll
        for (int j = 0; j < 8; j++){
            int s = half + (j << 1);
            int byteoff = (2*u) ^ ((s & 7) << 4);
            *(unsigned short*)((char*)Hs + (s << 9) + byteoff) = f2bf(hreg[j]);
        }
        __syncthreads();

        // (D) async-prefetch this step's xg rows into LDS (drains at next barrier,
        // latency hidden under the MFMA block)
        #pragma unroll
        for (int q = 0; q < 2; q++){
            int s = wid*2 + q;
            if (st_seg[s] >= 0){
                int row = st_bv[s]*S_ + st_t[s];
                const unsigned short* src = xg + (size_t)row*G3_ + lane*2;
                #pragma unroll
                for (int i = 0; i < 6; i++)
                    async_cp4(src + i*128, &xgbuf[s][i*128]);
            }
        }

        // (E) hg[slot][colp] = H @ W'   (M=16 slots, K=256, N-slice 96/wave)
        {
            f32x4 acc6[6];
            #pragma unroll
            for (int nf = 0; nf < 6; nf++) acc6[nf] = (f32x4){0.f,0.f,0.f,0.f};
            #pragma unroll
            for (int kf = 0; kf < 8; kf++){
                int boff = (kf*64 + l4*16) ^ ((l15 & 7) << 4);
                bf16x8 a = *(const bf16x8*)((const char*)Hs + (l15 << 9) + boff);
                #pragma unroll
                for (int nf = 0; nf < 6; nf++)
                    acc6[nf] = __builtin_amdgcn_mfma_f32_16x16x32_bf16(a, wf[kf*6 + nf], acc6[nf], 0, 0, 0);
            }
            #pragma unroll
            for (int nf = 0; nf < 6; nf++)
                #pragma unroll
                for (int r = 0; r < 4; r++)
                    hg[l4*4 + r][wid*96 + nf*16 + l15] = acc6[nf][r];
        }
        __syncthreads();

        // (F) gates (xg from LDS prefetch)
        #pragma unroll
        for (int j = 0; j < 8; j++){
            int s = half + (j << 1);
            if (st_seg[s] < 0) continue;
            int t = st_t[s], bb = st_bv[s];
            int row = bb*S_ + t;
            float hgr = hg[s][3*u]     + bhr;
            float hgz = hg[s][3*u + 1] + bhz;
            float hgn = hg[s][3*u + 2] + bhn;
            float xrv = bf2f(xgbuf[s][u]);
            float xzv = bf2f(xgbuf[s][DN_ + u]);
            float xnv = bf2f(xgbuf[s][2*DN_ + u]);
            float rr  = sigf(xrv + hgr);
            float zz  = sigf(xzv + hgz);
            float nn2 = tanhfast(xnv + rr*hgn);
            float hn  = (1.f - zz)*nn2 + zz*hreg[j];
            hreg[j] = hn;
            out[(size_t)row*OUTC_ + 1 + u] = hn;
        }
        __syncthreads();

        // (G) state update + fused any-active barrier
        if (tid < NSLOT && st_seg[tid] >= 0){
            st_init[tid] = 0;
            int t = st_t[tid] + 1;
            if (t > st_endv[tid]){
                int nx = st_seg[tid] + SLOT_STRIDE;
                if (nx < cnt){
                    st_seg[tid] = nx; st_t[tid] = s_start[nx]; st_endv[tid] = s_end[nx];
                    st_bv[tid] = s_b[nx];
                    st_init[tid] = (s_src[nx] < 0) ? 1 : 2;
                } else st_seg[tid] = -1;
            } else st_t[tid] = t;
        }
        if (!__syncthreads_or(tid < NSLOT && st_seg[tid] >= 0)) break;
    }
}

// ---------------- time_center ----------------
__global__ void k_tc(float* __restrict__ out,
                     const int* __restrict__ bar, const float* __restrict__ com_t,
                     const float* __restrict__ hbs, const float* __restrict__ wv,
                     const float* __restrict__ bv_p, const float* __restrict__ W_time,
                     const float* __restrict__ b_time)
{
    int wid = threadIdx.x >> 6, lane = threadIdx.x & 63;
    int pos = blockIdx.x*4 + wid;
    int t = pos & (S_-1);
    if (bar[pos] == 0){
        if (lane == 0) out[(size_t)pos*OUTC_] = com_t[pos];
        return;
    }
    float bt = b_time[0];
    if (t == 0){
        if (lane == 0) out[(size_t)pos*OUTC_] = sigf(bt);
        return;
    }
    float dot = 0.f;
    bool barprev = (bar[pos-1] == 0);
    if (barprev){
        const float* hb = hbs + (size_t)(pos-1)*DB_;
        #pragma unroll
        for (int i = 0; i < 4; i++) dot += hb[lane + 64*i]*wv[lane + 64*i];
    } else {
        const float* hp = out + (size_t)(pos-1)*OUTC_ + 1;
        #pragma unroll
        for (int i = 0; i < 4; i++) dot += hp[lane + 64*i]*W_time[lane + 64*i];
    }
    #pragma unroll
    for (int o = 32; o; o >>= 1) dot += __shfl_down(dot, o);
    if (lane == 0){
        if (barprev) dot += *bv_p;
        out[(size_t)pos*OUTC_] = sigf(dot + bt);
    }
}

// ---------------- launch ----------------
extern "C" void kernel_launch(void* const* d_in, const int* in_sizes, int n_in,
                              void* d_out, int out_size, void* d_ws, size_t ws_size,
                              hipStream_t stream) {
    const float* tgt    = (const float*)d_in[0];
    const float* hbs    = (const float*)d_in[1];
    const float* com_t  = (const float*)d_in[2];
    const float* W_in   = (const float*)d_in[3];
    const float* b_in   = (const float*)d_in[4];
    const float* W_init = (const float*)d_in[5];
    const float* b_init = (const float*)d_in[6];
    const float* W_ih   = (const float*)d_in[7];
    const float* b_ih   = (const float*)d_in[8];
    const float* W_hh   = (const float*)d_in[9];
    const float* b_hh   = (const float*)d_in[10];
    const float* W_time = (const float*)d_in[11];
    const float* b_time = (const float*)d_in[12];
    const int*   bar    = (const int*)d_in[13];
    float* out = (float*)d_out;

    char* ws = (char*)d_ws;
    size_t off = 0;
    auto alloc = [&](size_t bytes){ size_t o = off; off += (bytes + 255) & ~(size_t)255; return o; };
    size_t o_xg    = alloc((size_t)NPOS_*G3_*2);
    size_t o_wct   = alloc((size_t)G3_*DM_*2);
    size_t o_blob  = alloc((size_t)384*512*2);
    size_t o_reset = alloc((size_t)SEG_CAP*DN_*4);
    size_t o_bc    = alloc(G3_*4);
    size_t o_wv    = alloc(DN_*4);
    size_t o_bv    = alloc(4);
    size_t o_cnt   = alloc(4);
    size_t o_ss    = alloc(SEG_CAP*4);
    size_t o_se    = alloc(SEG_CAP*4);
    size_t o_sb    = alloc(SEG_CAP*4);
    size_t o_sr    = alloc(SEG_CAP*4);
    (void)ws_size; (void)in_sizes; (void)n_in; (void)out_size;

    unsigned short* xg   = (unsigned short*)(ws + o_xg);
    unsigned short* WcT  = (unsigned short*)(ws + o_wct);
    unsigned short* blob = (unsigned short*)(ws + o_blob);
    float* reset_buf = (float*)(ws + o_reset);
    float* bc = (float*)(ws + o_bc);
    float* wv = (float*)(ws + o_wv);
    float* bv = (float*)(ws + o_bv);
    int* cnt  = (int*)(ws + o_cnt);
    int* s_start = (int*)(ws + o_ss);
    int* s_end   = (int*)(ws + o_se);
    int* s_b     = (int*)(ws + o_sb);
    int* s_src   = (int*)(ws + o_sr);

    hipMemsetAsync(cnt, 0, 4, stream);

    k_prep_bc   <<<3, 256, 0, stream>>>(W_ih, b_ih, b_in, bc);
    k_prep_wct  <<<(G3_*DM_)/256, 256, 0, stream>>>(W_in, W_ih, WcT);
    k_prep_wfrag<<<96, 256, 0, stream>>>(W_hh, blob);
    k_prep_wv   <<<1, 256, 0, stream>>>(W_init, b_init, W_time, wv, bv);
    k_finder    <<<NPOS_/256, 256, 0, stream>>>(bar, cnt, s_start, s_end, s_b, s_src);
    k_reset     <<<512, 256, 0, stream>>>(hbs, W_init, b_init, cnt, s_src, reset_buf);
    k_gemm_xg   <<<(NPOS_/128)*6, 256, 0, stream>>>(tgt, WcT, bc, xg);
    k_scan      <<<SCAN_WGS, 512, 0, stream>>>(xg, blob, reset_buf, b_hh,
                                               cnt, s_start, s_end, s_b, s_src, out);
    k_tc        <<<NPOS_/4, 256, 0, stream>>>(out, bar, com_t, hbs, wv, bv, W_time, b_time);
}